// Round 15
// baseline (51.577 us; speedup 1.0000x reference)
//
#include <hip/hip_runtime.h>
#include <stdint.h>
#include <stddef.h>

// ---- problem constants ----
#define NBATCH 2
#define NPTS   120000
#define T_SLOTS 100
#define PMAX   12000
#define NXG    500
#define NYG    500
#define NBINS  (NXG*NYG)            // 250000
#define NCH    ((NBINS + 63)/64)    // 3907 64-bin chunks per batch
#define NG     ((NCH + 63)/64)      // 62 chunk-groups per batch

#define FEAT_BLOCKS 3000            // 12000 waves x 2 pillars = 24000

// ---- workspace layout (bytes) ----
// zero region: [flags][ticket] at base (500,016 B, 16B-divisible)
#define WS_FLAGS   ((size_t)0)                                  // 2*NBINS = 500,000
#define WS_TICKET  (WS_FLAGS + (size_t)NBATCH*NBINS)            // 16 B (4 used)
#define WS_ZEROEND (WS_TICKET + 16)                              // 500,016
#define WS_SLOT    (WS_ZEROEND)                                  // 2*PMAX*4 = 96,000 (zeroed in k_scan)
#define WS_MASKS   (WS_SLOT  + (size_t)NBATCH*PMAX*4)           // 2*NCH*8 = 62,512 (8-aligned)
#define WS_PDAT    (WS_MASKS + (size_t)NBATCH*NCH*8)            // 2*PMAX*T*16 = 38,400,000 (16-aligned)
#define WS_CHOFF   (WS_PDAT  + (size_t)NBATCH*PMAX*T_SLOTS*16)  // 2*NCH*4
#define WS_PILKEY  (WS_CHOFF + (size_t)NBATCH*NCH*4)            // 2*PMAX*4
#define WS_GRPS    (WS_PILKEY+ (size_t)NBATCH*PMAX*4)           // 2*NG*4 (plain stores, no zeroing)
#define WS_PTOT    (WS_GRPS  + (size_t)NBATCH*NG*4)             // 2*4
#define WS_NEEDED  (WS_PTOT  + (size_t)NBATCH*4)

#define ZERO_F4    (WS_ZEROEND / 16)   // 31,251 float4 stores

// ---------------- kernels ----------------

__global__ void k_zero(float4* __restrict__ dst) {
    int i = blockIdx.x * blockDim.x + threadIdx.x;
    if (i < (int)ZERO_F4) {
        float4 z; z.x = 0.0f; z.y = 0.0f; z.z = 0.0f; z.w = 0.0f;
        dst[i] = z;
    }
}

// presence flags via plain byte stores — zero atomics
__global__ void k_key(const float4* __restrict__ pts4,
                      unsigned char* __restrict__ flags) {
    int i = blockIdx.x * blockDim.x + threadIdx.x;
    if (i >= NBATCH * NPTS) return;
    int b = i / NPTS;
    float4 P = pts4[i];
    float x = P.x, y = P.y, z = P.z;
    bool valid = (x >= -40.0f) && (x < 40.0f) &&
                 (y >= -40.0f) && (y < 40.0f) &&
                 (z >= -3.0f)  && (z < 1.0f);
    if (valid) {
        float fx = floorf((x + 40.0f) / 0.16f);
        float fy = floorf((y + 40.0f) / 0.16f);
        fx = fminf(fmaxf(fx, 0.0f), (float)(NXG - 1));
        fy = fminf(fmaxf(fy, 0.0f), (float)(NYG - 1));
        int key = (int)fx * NYG + (int)fy;
        flags[(size_t)b * NBINS + key] = 1;
    }
}

// FUSED scan: 124 blocks do masks+grpsum (and zero slotctr); the LAST block
// (ticket election, decoupled-lookback ordering) computes group-prefixes,
// all chunk offsets and ptot. Replaces scanA+choff = one fewer dispatch.
__global__ __launch_bounds__(1024)
void k_scan(const unsigned char* __restrict__ flags,
            unsigned long long* __restrict__ masks,
            int* __restrict__ grpsum, int* __restrict__ choff,
            int* __restrict__ ptot, int* __restrict__ ticket,
            int* __restrict__ slotctr) {
    __shared__ int scnt[64];
    __shared__ int goff_s[NBATCH][64];
    __shared__ int amLast;
    const int g    = blockIdx.x;        // group 0..NG-1
    const int b    = blockIdx.y;        // batch
    const int tid  = threadIdx.x;
    const int lane = tid & 63;
    const int w    = tid >> 6;          // 0..15
    const unsigned char* fb = flags + (size_t)b * NBINS;

    // zero slotctr in parallel (runs before k_fill; kernel boundary orders it)
    {
        int idx = (b * NG + g) * 1024 + tid;
        if (idx < NBATCH * PMAX) slotctr[idx] = 0;
    }

    #pragma unroll
    for (int q = 0; q < 4; ++q) {
        int chl = w * 4 + q;            // local chunk 0..63
        int ch  = g * 64 + chl;
        int bin = ch * 64 + lane;
        int pres = (ch < NCH && bin < NBINS && fb[bin]) ? 1 : 0;
        unsigned long long m = __ballot(pres);
        if (lane == 0) {
            if (ch < NCH) masks[(size_t)b * NCH + ch] = m;
            scnt[chl] = __popcll(m);
        }
    }
    __syncthreads();
    if (w == 0) {
        int v = scnt[lane];
        #pragma unroll
        for (int off = 32; off > 0; off >>= 1) v += __shfl_xor(v, off);
        if (lane == 0) grpsum[b * NG + g] = v;
    }
    __syncthreads();                    // grpsum/masks stores issued

    // ---- last-block election ----
    if (tid == 0) {
        __threadfence();                // release masks+grpsum
        int t = atomicAdd(ticket, 1);
        amLast = (t == NBATCH * NG - 1);
    }
    __syncthreads();
    if (!amLast) return;
    __threadfence();                    // acquire other blocks' stores

    // ---- group prefix (one wave per batch) ----
    if (w < NBATCH) {
        int bb = w;
        int v = (lane < NG) ? grpsum[bb * NG + lane] : 0;
        int incl = v;
        #pragma unroll
        for (int off = 1; off < 64; off <<= 1) {
            int t2 = __shfl_up(incl, off);
            if (lane >= off) incl += t2;
        }
        if (lane < NG) goff_s[bb][lane] = incl - v;   // exclusive
        if (lane == NG - 1) ptot[bb] = incl;
    }
    __syncthreads();

    // ---- all chunk offsets (16 waves; ~4 iterations per wave per batch) ----
    for (int bb = 0; bb < NBATCH; ++bb) {
        for (int gg = w; gg < NG; gg += 16) {
            int ch = gg * 64 + lane;
            unsigned long long m = (ch < NCH) ? masks[(size_t)bb * NCH + ch] : 0ULL;
            int cs = __popcll(m);
            int ex = cs;
            #pragma unroll
            for (int off = 1; off < 64; off <<= 1) {
                int t2 = __shfl_up(ex, off);
                if (lane >= off) ex += t2;
            }
            ex -= cs;                                   // exclusive
            if (ch < NCH) choff[(size_t)bb * NCH + ch] = goff_s[bb][gg] + ex;
        }
    }
}

// fill: recompute key; rank via mask popcount; spread ticket atomics.
// Stores POINT DATA into slots (pdat) so k_feats needs no gather chain.
__global__ void k_fill(const float4* __restrict__ pts4,
                       const unsigned long long* __restrict__ masks,
                       const int* __restrict__ choff, int* __restrict__ slotctr,
                       int* __restrict__ pilkey, float4* __restrict__ pdat) {
    int i = blockIdx.x * blockDim.x + threadIdx.x;
    if (i >= NBATCH * NPTS) return;
    int b = i / NPTS;
    float4 P = pts4[i];
    float x = P.x, y = P.y, z = P.z;
    bool valid = (x >= -40.0f) && (x < 40.0f) &&
                 (y >= -40.0f) && (y < 40.0f) &&
                 (z >= -3.0f)  && (z < 1.0f);
    if (!valid) return;
    float fx = floorf((x + 40.0f) / 0.16f);
    float fy = floorf((y + 40.0f) / 0.16f);
    fx = fminf(fmaxf(fx, 0.0f), (float)(NXG - 1));
    fy = fminf(fmaxf(fy, 0.0f), (float)(NYG - 1));
    int key = (int)fx * NYG + (int)fy;

    int ch = key >> 6;
    unsigned long long m = masks[(size_t)b * NCH + ch];
    int r = choff[(size_t)b * NCH + ch] +
            __popcll(m & ((1ULL << (key & 63)) - 1ULL));
    if (r >= PMAX) return;
    pilkey[b * PMAX + r] = key;     // all writers store the same value
    int t = atomicAdd(&slotctr[b * PMAX + r], 1);
    if (t < T_SLOTS)
        pdat[((size_t)(b * PMAX + r)) * T_SLOTS + t] = P;
}

// TWO pillars per wave (same r, batch 0 and batch 1): each w2s quad read
// feeds both pillars' phase-B FMAs (k_feats is LDS-BW-bound; r14 win).
__global__ __launch_bounds__(256, 8)
void k_feats(const float4* __restrict__ pdat,
             const float* __restrict__ w1, const float* __restrict__ g1,
             const float* __restrict__ b1, const float* __restrict__ m1,
             const float* __restrict__ v1,
             const float* __restrict__ w2, const float* __restrict__ g2,
             const float* __restrict__ b2, const float* __restrict__ m2,
             const float* __restrict__ v2,
             const int* __restrict__ pilkey, const int* __restrict__ slotctr,
             const int* __restrict__ ptot, float* __restrict__ out) {
    __shared__ float4 w2s[16 * 64];                    // [kq][o], 16 KB
    __shared__ __align__(16) float h1s[4][2][64];      // [wave][pillar][chan]

    const int tid  = threadIdx.x;
    const int lane = tid & 63;
    const int widx = tid >> 6;
    const int o = lane;

    float* feats  = out;                                   // [B][PMAX][64]
    float* coords = out + (size_t)NBATCH * PMAX * 64;      // [B][PMAX][3]

    const int r  = blockIdx.x * 4 + widx;  // 0..11999
    const int pA = r;                      // batch 0
    const int pB = r + PMAX;               // batch 1

    // independent early loads
    const float4* prowA = pdat + (size_t)pA * T_SLOTS;
    const float4* prowB = pdat + (size_t)pB * T_SLOTS;
    int keyA = pilkey[pA], keyB = pilkey[pB];
    int cA   = slotctr[pA], cB = slotctr[pB];
    int pe0 = ptot[0]; if (pe0 > PMAX) pe0 = PMAX;
    int pe1 = ptot[1]; if (pe1 > PMAX) pe1 = PMAX;

    // ---- layer-1 folded weights ----
    float s1 = g1[o] * rsqrtf(v1[o] + 1e-5f);
    float b1f = b1[o] - m1[o] * s1;
    float w1r[8];
    {
        const float4* w14 = (const float4*)(w1 + o * 8);
        float4 a = w14[0], c4 = w14[1];
        w1r[0] = a.x * s1;  w1r[1] = a.y * s1;  w1r[2] = a.z * s1;  w1r[3] = a.w * s1;
        w1r[4] = c4.x * s1; w1r[5] = c4.y * s1; w1r[6] = c4.z * s1; w1r[7] = c4.w * s1;
    }
    float wx = w1r[0] + w1r[6];            // fold x_off into x
    float wy = w1r[1] + w1r[7];            // fold y_off into y

    // ---- stage folded w2 into LDS ----
    float s2 = g2[o] * rsqrtf(v2[o] + 1e-5f);
    float b2f = b2[o] - m2[o] * s2;
    {
        const float4* w2row = (const float4*)(w2 + o * 64);
        #pragma unroll
        for (int it = 0; it < 4; ++it) {
            int kq = widx + it * 4;
            float4 t = w2row[kq];
            t.x *= s2; t.y *= s2; t.z *= s2; t.w *= s2;
            w2s[kq * 64 + o] = t;
        }
    }
    __syncthreads();   // one-time; all waves converged

    // per-pillar derived values
    int xiA = keyA / NYG, yiA = keyA - xiA * NYG;
    int xiB = keyB / NYG, yiB = keyB - xiB * NYG;
    float xcA = (float)xiA * 0.16f - 40.0f + 0.08f;
    float ycA = (float)yiA * 0.16f - 40.0f + 0.08f;
    float xcB = (float)xiB * 0.16f - 40.0f + 0.08f;
    float ycB = (float)yiB * 0.16f - 40.0f + 0.08f;
    float pbA = b1f + (w1r[4] - w1r[6]) * xcA + (w1r[5] - w1r[7]) * ycA;
    float pbB = b1f + (w1r[4] - w1r[6]) * xcB + (w1r[5] - w1r[7]) * ycB;

    bool liveA = (r < pe0), liveB = (r < pe1);
    int pcA = liveA ? ((cA < T_SLOTS) ? cA : T_SLOTS) : 0;
    int pcB = liveB ? ((cB < T_SLOTS) ? cB : T_SLOTS) : 0;
    int nItA = liveA ? (pcA + ((cA < T_SLOTS) ? 1 : 0)) : 0;
    int nItB = liveB ? (pcB + ((cB < T_SLOTS) ? 1 : 0)) : 0;
    int maxN = (nItA > nItB) ? nItA : nItB;

    float accA = 0.0f, accB = 0.0f;   // slot outputs are post-ReLU (>=0)

    for (int s = 0; s < maxN; ++s) {
        float4 PA, PB;
        if (s < pcA) PA = prowA[s];
        else { PA.x = 0.0f; PA.y = 0.0f; PA.z = 0.0f; PA.w = 0.0f; }
        if (s < pcB) PB = prowB[s];
        else { PB.x = 0.0f; PB.y = 0.0f; PB.z = 0.0f; PB.w = 0.0f; }

        float hA = pbA;
        hA += wx * PA.x; hA += wy * PA.y;
        hA += w1r[2] * PA.z; hA += w1r[3] * PA.w;
        hA = fmaxf(hA, 0.0f);
        float hB = pbB;
        hB += wx * PB.x; hB += wy * PB.y;
        hB += w1r[2] * PB.z; hB += w1r[3] * PB.w;
        hB = fmaxf(hB, 0.0f);

        h1s[widx][0][o] = hA;                   // wave-synchronous broadcast
        h1s[widx][1][o] = hB;
        asm volatile("s_waitcnt lgkmcnt(0)" ::: "memory");

        float aA0 = b2f, aA1 = 0.0f, aB0 = b2f, aB1 = 0.0f;
        #pragma unroll
        for (int kq = 0; kq < 16; ++kq) {
            float4 w  = w2s[kq * 64 + o];       // shared by both pillars
            float4 qA = *(const float4*)&h1s[widx][0][kq * 4];
            float4 qB = *(const float4*)&h1s[widx][1][kq * 4];
            aA0 += w.x * qA.x; aA1 += w.y * qA.y;
            aA0 += w.z * qA.z; aA1 += w.w * qA.w;
            aB0 += w.x * qB.x; aB1 += w.y * qB.y;
            aB0 += w.z * qB.z; aB1 += w.w * qB.w;
        }
        if (s < nItA) accA = fmaxf(accA, fmaxf(aA0 + aA1, 0.0f));
        if (s < nItB) accB = fmaxf(accB, fmaxf(aB0 + aB1, 0.0f));
    }

    // epilogue
    size_t frowA = (size_t)pA * 64, crowA = (size_t)pA * 3;
    size_t frowB = (size_t)pB * 64, crowB = (size_t)pB * 3;
    feats[frowA + o] = liveA ? accA : 0.0f;
    feats[frowB + o] = liveB ? accB : 0.0f;
    if (o < 3) {
        coords[crowA + o] = liveA
            ? ((o == 0) ? 0.0f : (o == 1) ? (float)xiA : (float)yiA)
            : 0.0f;
        coords[crowB + o] = liveB
            ? ((o == 0) ? 1.0f : (o == 1) ? (float)xiB : (float)yiB)
            : ((o == 0) ? 1.0f : 0.0f);
    }
}

// ---------------- launcher ----------------

extern "C" void kernel_launch(void* const* d_in, const int* in_sizes, int n_in,
                              void* d_out, int out_size, void* d_ws, size_t ws_size,
                              hipStream_t stream) {
    if (ws_size < WS_NEEDED) return;   // safety

    const float4* pts4 = (const float4*)d_in[0];
    const float* w1  = (const float*)d_in[1];
    const float* g1  = (const float*)d_in[2];
    const float* b1  = (const float*)d_in[3];
    const float* m1  = (const float*)d_in[4];
    const float* v1  = (const float*)d_in[5];
    const float* w2  = (const float*)d_in[6];
    const float* g2  = (const float*)d_in[7];
    const float* b2  = (const float*)d_in[8];
    const float* m2  = (const float*)d_in[9];
    const float* v2  = (const float*)d_in[10];

    char* ws = (char*)d_ws;
    unsigned char* flags = (unsigned char*)(ws + WS_FLAGS);
    int*  ticket  = (int*)(ws + WS_TICKET);
    int*  slotctr = (int*)(ws + WS_SLOT);
    unsigned long long* masks = (unsigned long long*)(ws + WS_MASKS);
    float4* pdat  = (float4*)(ws + WS_PDAT);
    int*  choff   = (int*)(ws + WS_CHOFF);
    int*  pilkey  = (int*)(ws + WS_PILKEY);
    int*  grpsum  = (int*)(ws + WS_GRPS);
    int*  ptot    = (int*)(ws + WS_PTOT);
    float* out    = (float*)d_out;

    dim3 blk256(256);
    int npt = NBATCH * NPTS;
    dim3 grdPts((npt + 255) / 256);

    // 1) zero flags+ticket (500 KB)
    hipLaunchKernelGGL(k_zero, dim3((ZERO_F4 + 255) / 256), blk256, 0, stream,
                       (float4*)(ws + WS_FLAGS));

    // 2) presence flags (no atomics)
    hipLaunchKernelGGL(k_key, grdPts, blk256, 0, stream, pts4, flags);

    // 3) fused scan: masks + grpsum + (last block) choff + ptot; zeros slotctr
    hipLaunchKernelGGL(k_scan, dim3(NG, NBATCH), dim3(1024), 0, stream,
                       flags, masks, grpsum, choff, ptot, ticket, slotctr);

    // 4) fill slots with point DATA
    hipLaunchKernelGGL(k_fill, grdPts, blk256, 0, stream,
                       pts4, masks, choff, slotctr, pilkey, pdat);

    // 5) pillar features (2 pillars per wave)
    hipLaunchKernelGGL(k_feats, dim3(FEAT_BLOCKS), blk256, 0, stream,
                       pdat, w1, g1, b1, m1, v1, w2, g2, b2, m2, v2,
                       pilkey, slotctr, ptot, out);
}

// Round 16
// 43.042 us; speedup vs baseline: 1.1983x; 1.1983x over previous
//
#include <hip/hip_runtime.h>
#include <stdint.h>
#include <stddef.h>

// ---- problem constants ----
#define NBATCH 2
#define NPTS   120000
#define T_SLOTS 100
#define PMAX   12000
#define NXG    500
#define NYG    500
#define NBINS  (NXG*NYG)            // 250000
#define NCH    ((NBINS + 63)/64)    // 3907 64-bin chunks per batch
#define NG     ((NCH + 63)/64)      // 62 chunk-groups per batch

#define FEAT_BLOCKS 3000            // 12000 waves x 2 pillars = 24000

// ---- workspace layout (bytes) ----
// zero region: [flags][slotctr] contiguous at base (596,000 B, 16B-divisible)
#define WS_FLAGS   ((size_t)0)                                  // 2*NBINS   = 500,000
#define WS_SLOT    (WS_FLAGS + (size_t)NBATCH*NBINS)            // 2*PMAX*4  =  96,000
#define WS_ZEROEND (WS_SLOT  + (size_t)NBATCH*PMAX*4)           // 596,000
#define WS_MASKS   (WS_ZEROEND)                                  // 2*NCH*8  = 62,512
#define WS_PDAT    (WS_MASKS + (size_t)NBATCH*NCH*8)            // 2*PMAX*T*16 = 38,400,000
#define WS_CHOFF   (WS_PDAT  + (size_t)NBATCH*PMAX*T_SLOTS*16)  // 2*NCH*4
#define WS_PILKEY  (WS_CHOFF + (size_t)NBATCH*NCH*4)            // 2*PMAX*4
#define WS_GRPS    (WS_PILKEY+ (size_t)NBATCH*PMAX*4)           // 2*NG*4 (no zeroing needed)
#define WS_PTOT    (WS_GRPS  + (size_t)NBATCH*NG*4)             // 2*4
#define WS_NEEDED  (WS_PTOT  + (size_t)NBATCH*4)

#define ZERO_F4    (WS_ZEROEND / 16)   // 37,250 float4 stores

// ---------------- kernels ----------------

__global__ void k_zero(float4* __restrict__ dst) {
    int i = blockIdx.x * blockDim.x + threadIdx.x;
    if (i < (int)ZERO_F4) {
        float4 z; z.x = 0.0f; z.y = 0.0f; z.z = 0.0f; z.w = 0.0f;
        dst[i] = z;
    }
}

// presence flags via plain byte stores — zero atomics
__global__ void k_key(const float4* __restrict__ pts4,
                      unsigned char* __restrict__ flags) {
    int i = blockIdx.x * blockDim.x + threadIdx.x;
    if (i >= NBATCH * NPTS) return;
    int b = i / NPTS;
    float4 P = pts4[i];
    float x = P.x, y = P.y, z = P.z;
    bool valid = (x >= -40.0f) && (x < 40.0f) &&
                 (y >= -40.0f) && (y < 40.0f) &&
                 (z >= -3.0f)  && (z < 1.0f);
    if (valid) {
        float fx = floorf((x + 40.0f) / 0.16f);
        float fy = floorf((y + 40.0f) / 0.16f);
        fx = fminf(fmaxf(fx, 0.0f), (float)(NXG - 1));
        fy = fminf(fmaxf(fy, 0.0f), (float)(NYG - 1));
        int key = (int)fx * NYG + (int)fy;
        flags[(size_t)b * NBINS + key] = 1;
    }
}

// WIDE scan stage A: one block per (group, batch) = 124 blocks.
__global__ __launch_bounds__(1024)
void k_scanA(const unsigned char* __restrict__ flags,
             unsigned long long* __restrict__ masks,
             int* __restrict__ grpsum) {
    __shared__ int scnt[64];
    const int g    = blockIdx.x;        // group 0..NG-1
    const int b    = blockIdx.y;        // batch
    const int tid  = threadIdx.x;
    const int lane = tid & 63;
    const int w    = tid >> 6;          // 0..15
    const unsigned char* fb = flags + (size_t)b * NBINS;

    #pragma unroll
    for (int q = 0; q < 4; ++q) {
        int chl = w * 4 + q;            // local chunk 0..63
        int ch  = g * 64 + chl;
        int bin = ch * 64 + lane;
        int pres = (ch < NCH && bin < NBINS && fb[bin]) ? 1 : 0;
        unsigned long long m = __ballot(pres);
        if (lane == 0) {
            if (ch < NCH) masks[(size_t)b * NCH + ch] = m;
            scnt[chl] = __popcll(m);
        }
    }
    __syncthreads();
    if (w == 0) {
        int v = scnt[lane];
        #pragma unroll
        for (int off = 32; off > 0; off >>= 1) v += __shfl_xor(v, off);
        if (lane == 0) grpsum[b * NG + g] = v;
    }
}

// chunk offsets: one wave per (batch, group). HW-verified rounds 9/10/12/13/14.
__global__ void k_choff(const unsigned long long* __restrict__ masks,
                        const int* __restrict__ grpsum,
                        int* __restrict__ choff, int* __restrict__ ptot) {
    int tid  = threadIdx.x;
    int lane = tid & 63;
    int gw   = blockIdx.x * 4 + (tid >> 6);
    if (gw >= NBATCH * NG) return;
    int b = gw / NG, g = gw - b * NG;

    int gs = (lane < NG) ? grpsum[b * NG + lane] : 0;
    int incl = gs;
    #pragma unroll
    for (int off = 1; off < 64; off <<= 1) {
        int t2 = __shfl_up(incl, off);
        if (lane >= off) incl += t2;
    }
    int tot  = __shfl(incl, NG - 1);                  // all lanes execute
    int goff = __shfl(incl, (g == 0) ? 0 : g - 1);    // all lanes execute
    if (g == 0) goff = 0;
    if (g == 0 && lane == 0) ptot[b] = tot;

    int ch = g * 64 + lane;
    int cs = (ch < NCH) ? __popcll(masks[(size_t)b * NCH + ch]) : 0;
    int incl2 = cs;
    #pragma unroll
    for (int off = 1; off < 64; off <<= 1) {
        int t2 = __shfl_up(incl2, off);
        if (lane >= off) incl2 += t2;
    }
    if (ch < NCH) choff[(size_t)b * NCH + ch] = goff + incl2 - cs;
}

// fill: recompute key; rank via mask popcount; spread ticket atomics.
// Stores POINT DATA into slots (pdat) so k_feats needs no gather chain.
__global__ void k_fill(const float4* __restrict__ pts4,
                       const unsigned long long* __restrict__ masks,
                       const int* __restrict__ choff, int* __restrict__ slotctr,
                       int* __restrict__ pilkey, float4* __restrict__ pdat) {
    int i = blockIdx.x * blockDim.x + threadIdx.x;
    if (i >= NBATCH * NPTS) return;
    int b = i / NPTS;
    float4 P = pts4[i];
    float x = P.x, y = P.y, z = P.z;
    bool valid = (x >= -40.0f) && (x < 40.0f) &&
                 (y >= -40.0f) && (y < 40.0f) &&
                 (z >= -3.0f)  && (z < 1.0f);
    if (!valid) return;
    float fx = floorf((x + 40.0f) / 0.16f);
    float fy = floorf((y + 40.0f) / 0.16f);
    fx = fminf(fmaxf(fx, 0.0f), (float)(NXG - 1));
    fy = fminf(fmaxf(fy, 0.0f), (float)(NYG - 1));
    int key = (int)fx * NYG + (int)fy;

    int ch = key >> 6;
    unsigned long long m = masks[(size_t)b * NCH + ch];
    int r = choff[(size_t)b * NCH + ch] +
            __popcll(m & ((1ULL << (key & 63)) - 1ULL));
    if (r >= PMAX) return;
    pilkey[b * PMAX + r] = key;     // all writers store the same value
    int t = atomicAdd(&slotctr[b * PMAX + r], 1);
    if (t < T_SLOTS)
        pdat[((size_t)(b * PMAX + r)) * T_SLOTS + t] = P;
}

// TWO pillars per wave (same r, batch 0 and batch 1): each w2s quad read
// feeds both pillars' phase-B FMAs -> LDS w2 traffic halves (k_feats is
// LDS-BW-bound after r13 removed the gather chain).
__global__ __launch_bounds__(256, 8)
void k_feats(const float4* __restrict__ pdat,
             const float* __restrict__ w1, const float* __restrict__ g1,
             const float* __restrict__ b1, const float* __restrict__ m1,
             const float* __restrict__ v1,
             const float* __restrict__ w2, const float* __restrict__ g2,
             const float* __restrict__ b2, const float* __restrict__ m2,
             const float* __restrict__ v2,
             const int* __restrict__ pilkey, const int* __restrict__ slotctr,
             const int* __restrict__ ptot, float* __restrict__ out) {
    __shared__ float4 w2s[16 * 64];                    // [kq][o], 16 KB
    __shared__ __align__(16) float h1s[4][2][64];      // [wave][pillar][chan], 2 KB

    const int tid  = threadIdx.x;
    const int lane = tid & 63;
    const int widx = tid >> 6;
    const int o = lane;

    float* feats  = out;                                   // [B][PMAX][64]
    float* coords = out + (size_t)NBATCH * PMAX * 64;      // [B][PMAX][3]

    const int r  = blockIdx.x * 4 + widx;  // 0..11999
    const int pA = r;                      // batch 0
    const int pB = r + PMAX;               // batch 1

    // independent early loads
    const float4* prowA = pdat + (size_t)pA * T_SLOTS;
    const float4* prowB = pdat + (size_t)pB * T_SLOTS;
    int keyA = pilkey[pA], keyB = pilkey[pB];
    int cA   = slotctr[pA], cB = slotctr[pB];
    int pe0 = ptot[0]; if (pe0 > PMAX) pe0 = PMAX;
    int pe1 = ptot[1]; if (pe1 > PMAX) pe1 = PMAX;

    // ---- layer-1 folded weights ----
    float s1 = g1[o] * rsqrtf(v1[o] + 1e-5f);
    float b1f = b1[o] - m1[o] * s1;
    float w1r[8];
    {
        const float4* w14 = (const float4*)(w1 + o * 8);
        float4 a = w14[0], c4 = w14[1];
        w1r[0] = a.x * s1;  w1r[1] = a.y * s1;  w1r[2] = a.z * s1;  w1r[3] = a.w * s1;
        w1r[4] = c4.x * s1; w1r[5] = c4.y * s1; w1r[6] = c4.z * s1; w1r[7] = c4.w * s1;
    }
    float wx = w1r[0] + w1r[6];            // fold x_off into x
    float wy = w1r[1] + w1r[7];            // fold y_off into y

    // ---- stage folded w2 into LDS ----
    float s2 = g2[o] * rsqrtf(v2[o] + 1e-5f);
    float b2f = b2[o] - m2[o] * s2;
    {
        const float4* w2row = (const float4*)(w2 + o * 64);
        #pragma unroll
        for (int it = 0; it < 4; ++it) {
            int kq = widx + it * 4;
            float4 t = w2row[kq];
            t.x *= s2; t.y *= s2; t.z *= s2; t.w *= s2;
            w2s[kq * 64 + o] = t;
        }
    }
    __syncthreads();   // one-time; all waves converged

    // per-pillar derived values
    int xiA = keyA / NYG, yiA = keyA - xiA * NYG;
    int xiB = keyB / NYG, yiB = keyB - xiB * NYG;
    float xcA = (float)xiA * 0.16f - 40.0f + 0.08f;
    float ycA = (float)yiA * 0.16f - 40.0f + 0.08f;
    float xcB = (float)xiB * 0.16f - 40.0f + 0.08f;
    float ycB = (float)yiB * 0.16f - 40.0f + 0.08f;
    float pbA = b1f + (w1r[4] - w1r[6]) * xcA + (w1r[5] - w1r[7]) * ycA;
    float pbB = b1f + (w1r[4] - w1r[6]) * xcB + (w1r[5] - w1r[7]) * ycB;

    bool liveA = (r < pe0), liveB = (r < pe1);
    int pcA = liveA ? ((cA < T_SLOTS) ? cA : T_SLOTS) : 0;
    int pcB = liveB ? ((cB < T_SLOTS) ? cB : T_SLOTS) : 0;
    int nItA = liveA ? (pcA + ((cA < T_SLOTS) ? 1 : 0)) : 0;
    int nItB = liveB ? (pcB + ((cB < T_SLOTS) ? 1 : 0)) : 0;
    int maxN = (nItA > nItB) ? nItA : nItB;

    float accA = 0.0f, accB = 0.0f;   // slot outputs are post-ReLU (>=0)

    for (int s = 0; s < maxN; ++s) {
        float4 PA, PB;
        if (s < pcA) PA = prowA[s];
        else { PA.x = 0.0f; PA.y = 0.0f; PA.z = 0.0f; PA.w = 0.0f; }
        if (s < pcB) PB = prowB[s];
        else { PB.x = 0.0f; PB.y = 0.0f; PB.z = 0.0f; PB.w = 0.0f; }

        float hA = pbA;
        hA += wx * PA.x; hA += wy * PA.y;
        hA += w1r[2] * PA.z; hA += w1r[3] * PA.w;
        hA = fmaxf(hA, 0.0f);
        float hB = pbB;
        hB += wx * PB.x; hB += wy * PB.y;
        hB += w1r[2] * PB.z; hB += w1r[3] * PB.w;
        hB = fmaxf(hB, 0.0f);

        h1s[widx][0][o] = hA;                   // wave-synchronous broadcast
        h1s[widx][1][o] = hB;
        asm volatile("s_waitcnt lgkmcnt(0)" ::: "memory");

        float aA0 = b2f, aA1 = 0.0f, aB0 = b2f, aB1 = 0.0f;
        #pragma unroll
        for (int kq = 0; kq < 16; ++kq) {
            float4 w  = w2s[kq * 64 + o];       // shared by both pillars
            float4 qA = *(const float4*)&h1s[widx][0][kq * 4];
            float4 qB = *(const float4*)&h1s[widx][1][kq * 4];
            aA0 += w.x * qA.x; aA1 += w.y * qA.y;
            aA0 += w.z * qA.z; aA1 += w.w * qA.w;
            aB0 += w.x * qB.x; aB1 += w.y * qB.y;
            aB0 += w.z * qB.z; aB1 += w.w * qB.w;
        }
        if (s < nItA) accA = fmaxf(accA, fmaxf(aA0 + aA1, 0.0f));
        if (s < nItB) accB = fmaxf(accB, fmaxf(aB0 + aB1, 0.0f));
    }

    // epilogue
    size_t frowA = (size_t)pA * 64, crowA = (size_t)pA * 3;
    size_t frowB = (size_t)pB * 64, crowB = (size_t)pB * 3;
    feats[frowA + o] = liveA ? accA : 0.0f;
    feats[frowB + o] = liveB ? accB : 0.0f;
    if (o < 3) {
        coords[crowA + o] = liveA
            ? ((o == 0) ? 0.0f : (o == 1) ? (float)xiA : (float)yiA)
            : 0.0f;
        coords[crowB + o] = liveB
            ? ((o == 0) ? 1.0f : (o == 1) ? (float)xiB : (float)yiB)
            : ((o == 0) ? 1.0f : 0.0f);
    }
}

// ---------------- launcher ----------------

extern "C" void kernel_launch(void* const* d_in, const int* in_sizes, int n_in,
                              void* d_out, int out_size, void* d_ws, size_t ws_size,
                              hipStream_t stream) {
    if (ws_size < WS_NEEDED) return;   // safety

    const float4* pts4 = (const float4*)d_in[0];
    const float* w1  = (const float*)d_in[1];
    const float* g1  = (const float*)d_in[2];
    const float* b1  = (const float*)d_in[3];
    const float* m1  = (const float*)d_in[4];
    const float* v1  = (const float*)d_in[5];
    const float* w2  = (const float*)d_in[6];
    const float* g2  = (const float*)d_in[7];
    const float* b2  = (const float*)d_in[8];
    const float* m2  = (const float*)d_in[9];
    const float* v2  = (const float*)d_in[10];

    char* ws = (char*)d_ws;
    unsigned char* flags = (unsigned char*)(ws + WS_FLAGS);
    int*  slotctr = (int*)(ws + WS_SLOT);
    unsigned long long* masks = (unsigned long long*)(ws + WS_MASKS);
    float4* pdat  = (float4*)(ws + WS_PDAT);
    int*  choff   = (int*)(ws + WS_CHOFF);
    int*  pilkey  = (int*)(ws + WS_PILKEY);
    int*  grpsum  = (int*)(ws + WS_GRPS);
    int*  ptot    = (int*)(ws + WS_PTOT);
    float* out    = (float*)d_out;

    dim3 blk256(256);
    int npt = NBATCH * NPTS;
    dim3 grdPts((npt + 255) / 256);

    // 1) zero flags+slotctr (596 KB)
    hipLaunchKernelGGL(k_zero, dim3((ZERO_F4 + 255) / 256), blk256, 0, stream,
                       (float4*)(ws + WS_FLAGS));

    // 2) presence flags (no atomics)
    hipLaunchKernelGGL(k_key, grdPts, blk256, 0, stream, pts4, flags);

    // 3) wide scan A: masks + group sums (124 blocks)
    hipLaunchKernelGGL(k_scanA, dim3(NG, NBATCH), dim3(1024), 0, stream,
                       flags, masks, grpsum);

    // 4) chunk offsets + ptot
    hipLaunchKernelGGL(k_choff, dim3((NBATCH * NG + 3) / 4), blk256, 0, stream,
                       masks, grpsum, choff, ptot);

    // 5) fill slots with point DATA
    hipLaunchKernelGGL(k_fill, grdPts, blk256, 0, stream,
                       pts4, masks, choff, slotctr, pilkey, pdat);

    // 6) pillar features (2 pillars per wave)
    hipLaunchKernelGGL(k_feats, dim3(FEAT_BLOCKS), blk256, 0, stream,
                       pdat, w1, g1, b1, m1, v1, w2, g2, b2, m2, v2,
                       pilkey, slotctr, ptot, out);
}